// Round 5
// baseline (251.547 us; speedup 1.0000x reference)
//
#include <hip/hip_runtime.h>
#include <hip/hip_bf16.h>
#include <stdint.h>

// Problem constants (match reference)
#define NN 50000      // nodes
#define NE 800000     // edges
#define NL 100000     // label edges
#define SLOTS 64      // padded-CSR slots/node (incl. appended self-loop)
#define PADROW 50000  // dedicated all-zero row index in every h-buffer

// Bucketed CSR build (R7: direct scatter was line-bound)
#define NB 196        // dst-range buckets: bucket = dst >> 8 (256 nodes each)
#define BSH 8
#define BCAP 5376     // edges/bucket capacity; mean 4082 -> +20 sigma

typedef __attribute__((ext_vector_type(8))) short bf16x8;   // MFMA A/B frag
typedef __attribute__((ext_vector_type(4))) float f32x4;    // MFMA C/D frag
typedef __attribute__((ext_vector_type(4))) unsigned int u32x4;
typedef __attribute__((ext_vector_type(2))) unsigned int u32x2;
typedef __attribute__((ext_vector_type(8))) unsigned short u16x8;

__device__ __forceinline__ float asf(unsigned int u) {
    union { unsigned int i; float f; } c; c.i = u; return c.f;
}
__device__ __forceinline__ float bflo(unsigned int x) { return asf(x << 16); }
__device__ __forceinline__ float bfhi(unsigned int x) { return asf(x & 0xffff0000u); }
__device__ __forceinline__ unsigned short f2bf(float f) {
    union { float f; unsigned int i; } c; c.f = f;
    unsigned int u = c.i + (0x7fffu + ((c.i >> 16) & 1u));
    return (unsigned short)(u >> 16);
}

// ---- P0: W transpose+convert to bf16 Wt[n][k]; zero cursors + pad rows ----
__global__ void k_wprep(const float* __restrict__ W1, const float* __restrict__ W2,
                        const float* __restrict__ W3, unsigned short* __restrict__ Wt,
                        int* __restrict__ cursor, unsigned int* __restrict__ padA,
                        unsigned int* __restrict__ padB) {
    int idx = blockIdx.x * 256 + threadIdx.x;   // grid exactly 160
    if (idx < NB) cursor[idx] = 0;
    if (idx < 64) padA[idx] = 0;
    else if (idx < 128) padB[idx - 64] = 0;
    const float* W; unsigned short* O; int base, Mloc;
    if (idx < 16384)      { W = W1; O = Wt;         base = idx;         Mloc = 128; }
    else if (idx < 32768) { W = W2; O = Wt + 16384; base = idx - 16384; Mloc = 128; }
    else                  { W = W3; O = Wt + 32768; base = idx - 32768; Mloc = 64;  }
    int n = base >> 7, k = base & 127;
    O[base] = f2bf(W[k * Mloc + n]);
}

// ---- P1: bin edges by dst range (LDS histogram -> packed NT writes) ----
__global__ __launch_bounds__(256) void k_bin(
        const int* __restrict__ src, const int* __restrict__ dst,
        int* __restrict__ cursor, unsigned int* __restrict__ binbuf) {
    __shared__ int hcnt[NB];
    __shared__ int hbase[NB];
    __shared__ unsigned int epk[2048];
    int tid = threadIdx.x;
    if (tid < NB) hcnt[tid] = 0;
    __syncthreads();
    int e0 = blockIdx.x * 2048;                 // grid exactly 391
    int e1 = min(e0 + 2048, NE);
    for (int e = e0 + tid; e < e1; e += 256) {
        int d = dst[e], s = src[e];
        atomicAdd(&hcnt[d >> BSH], 1);
        epk[e - e0] = (unsigned int)s | ((unsigned int)d << 16);
    }
    __syncthreads();
    if (tid < NB) { hbase[tid] = atomicAdd(&cursor[tid], hcnt[tid]); hcnt[tid] = 0; }
    __syncthreads();
    for (int e = e0 + tid; e < e1; e += 256) {
        unsigned int pk = epk[e - e0];
        int b = (int)(pk >> 16) >> BSH;
        int p = hbase[b] + atomicAdd(&hcnt[b], 1);
        if (p < BCAP)
            __builtin_nontemporal_store(pk, &binbuf[(size_t)b * BCAP + p]);
    }
}

// ---- P2: per-bucket CSR build in LDS + coalesced flush ----
// Pad slots = PADROW (zero row -> mask-free gathers); self-loop appended at
// slot p=deg. Slots < 32 PERMUTED: logical p at physical 8*(p&3)+(p>>2), so
// lane-group g's physical [8g,8g+8): element k2 <-> logical 4*k2+g.
__global__ __launch_bounds__(256) void k_csr(
        const unsigned int* __restrict__ binbuf, const int* __restrict__ cursor,
        int* __restrict__ deg, unsigned short* __restrict__ colp) {
    __shared__ unsigned short lcol[256 * SLOTS];   // 32 KB
    __shared__ int ldeg[256];
    int tid = threadIdx.x;
    int blk = blockIdx.x;                          // grid exactly NB
    int base = blk << BSH;
    int nNodes = min(256, NN - base);
    ldeg[tid] = 0;
    const unsigned int fw = 0xC350C350u;           // 2x 50000
    u32x4 fill = {fw, fw, fw, fw};
    u32x4* lz = (u32x4*)lcol;
#pragma unroll
    for (int i = 0; i < 8; ++i) lz[i * 256 + tid] = fill;
    __syncthreads();
    int cnt = min(cursor[blk], BCAP);
    for (int e = tid; e < cnt; e += 256) {
        unsigned int pk = __builtin_nontemporal_load(&binbuf[(size_t)blk * BCAP + e]);
        int d = (int)(pk >> 16) - base;
        int p = atomicAdd(&ldeg[d], 1);
        if (p < SLOTS) {
            int pp = (p < 32) ? ((p & 3) * 8 + (p >> 2)) : p;
            lcol[d * SLOTS + pp] = (unsigned short)(pk & 0xffffu);
        }
    }
    __syncthreads();
    if (tid < nNodes) {
        int dv = ldeg[tid];
        deg[base + tid] = dv;
        if (dv < SLOTS) {                          // append self-loop slot
            int pp = (dv < 32) ? ((dv & 3) * 8 + (dv >> 2)) : dv;
            lcol[tid * SLOTS + pp] = (unsigned short)(base + tid);
        }
    }
    __syncthreads();
    u32x4* gout = (u32x4*)(colp + (size_t)base * SLOTS);
    const u32x4* lin = (const u32x4*)lcol;
    for (int i = tid; i < nNodes * 8; i += 256) gout[i] = lin[i];
}

// ---- layer-1 GEMM: x (fp32) -> bufA (h1). Rows >= NN untouched (pad!) ----
__global__ __launch_bounds__(256) void k_gemm1(
        const float* __restrict__ A, const unsigned short* __restrict__ Wt,
        const int* __restrict__ deg, unsigned short* __restrict__ Outb, int N) {
    constexpr int K = 128;
    constexpr int NT = 8;
    int tid = threadIdx.x;
    int lane = tid & 63, wave = tid >> 6;
    int m = lane & 15, quad = lane >> 4;
    int rowA = blockIdx.x * 64 + wave * 16 + m;    // grid exactly 782
    int rA = min(rowA, N - 1);

    bf16x8 afr[4];
    const float* p = A + (size_t)rA * K + quad * 8;
#pragma unroll
    for (int s = 0; s < 4; ++s) {
        float4 lo = *(const float4*)(p + s * 32);
        float4 hi = *(const float4*)(p + s * 32 + 4);
        bf16x8 r;
        r[0] = (short)f2bf(lo.x); r[1] = (short)f2bf(lo.y);
        r[2] = (short)f2bf(lo.z); r[3] = (short)f2bf(lo.w);
        r[4] = (short)f2bf(hi.x); r[5] = (short)f2bf(hi.y);
        r[6] = (short)f2bf(hi.z); r[7] = (short)f2bf(hi.w);
        afr[s] = r;
    }

    f32x4 acc[NT];
#pragma unroll
    for (int t = 0; t < NT; ++t) { acc[t][0] = 0.f; acc[t][1] = 0.f; acc[t][2] = 0.f; acc[t][3] = 0.f; }
#pragma unroll
    for (int t = 0; t < NT; ++t) {
        const unsigned short* wp = Wt + (size_t)(t * 16 + m) * K + quad * 8;
#pragma unroll
        for (int s = 0; s < 4; ++s) {
            bf16x8 bfr = *(const bf16x8*)(wp + s * 32);
            acc[t] = __builtin_amdgcn_mfma_f32_16x16x32_bf16(afr[s], bfr, acc[t], 0, 0, 0);
        }
    }

    int outRowBase = blockIdx.x * 64 + wave * 16 + quad * 4;
    float di[4];
#pragma unroll
    for (int i = 0; i < 4; ++i) di[i] = rsqrtf((float)deg[min(outRowBase + i, N - 1)] + 1.0f);
#pragma unroll
    for (int t = 0; t < NT; ++t)
#pragma unroll
        for (int i = 0; i < 4; ++i) {
            int rr = outRowBase + i;
            if (rr < N) Outb[(size_t)rr * 128 + t * 16 + m] = f2bf(acc[t][i] * di[i]);
        }
}

// ---- FUSED agg+gemm (R17: 2-node pipeline, depth 5+5, (256,6)) ----
// R16 post-mortem: (256,8) let the compiler shrink the gather loop to ~32
// arch VGPRs (unified file shared with MFMA phase) -> ~2-3 loads in flight.
// R17: depth-5 batch A (logical slots 0..19, P(su<=20)=.81) and node t+1's
// batch issued BEFORE node t's accumulation -> 10 in flight steady-state.
// (256,6) caps at ~85 VGPR (est. peak 76, no spill), 6 waves/SIMD.
template <int M_>
__global__ __launch_bounds__(256, 6) void k_agg_gemm(
        const unsigned short* __restrict__ hs, const int* __restrict__ deg,
        const unsigned short* __restrict__ colp, const float* __restrict__ bias,
        const unsigned short* __restrict__ Wt, unsigned short* __restrict__ Outb) {
    constexpr int K = 128;          // agg feature width and gemm K
    constexpr int NT = M_ / 64;     // col tiles per wave: 128->2, 64->1
    __shared__ __align__(16) unsigned short As[16][136];
    int tid = threadIdx.x;
    int lane = tid & 63, wave = tid >> 6;
    int tileBase = blockIdx.x * 16;
    int g = lane >> 4, c = lane & 15;
    const unsigned short* hc = hs + c * 8;
    int nodeB = tileBase + wave * 4;

    int4 dg = *(const int4*)(deg + nodeB);         // 16B aligned
    int dgv[4] = {dg.x, dg.y, dg.z, dg.w};

    u16x8 slc = *(const u16x8*)(colp + (unsigned)nodeB * SLOTS + g * 8);
    u16x8 sln = *(const u16x8*)(colp + (unsigned)(nodeB + 1) * SLOTS + g * 8);

    u32x4 vcur[5];
#pragma unroll
    for (int k2 = 0; k2 < 5; ++k2)
        vcur[k2] = *(const u32x4*)(hc + (unsigned)slc[k2] * K);

    // ---- agg phase: wave aggregates rows wave*4 .. wave*4+3 ----
#pragma unroll
    for (int t = 0; t < 4; ++t) {
        int node = nodeB + t;
        int su = min(dgv[t] + 1, SLOTS);           // slots incl. self

        u32x4 vnxt[5];
        if (t < 3) {                               // issue next node's batch A
#pragma unroll
            for (int k2 = 0; k2 < 5; ++k2)
                vnxt[k2] = *(const u32x4*)(hc + (unsigned)sln[k2] * K);
        }
        u16x8 sl2 = sln;
        if (t < 2)                                 // slot list for node t+2
            sl2 = *(const u16x8*)(colp + (unsigned)(node + 2) * SLOTS + g * 8);

        float acc[8];
#pragma unroll
        for (int k = 0; k < 8; ++k) acc[k] = 0.f;
#pragma unroll
        for (int k2 = 0; k2 < 5; ++k2)
#pragma unroll
            for (int k = 0; k < 4; ++k) {
                acc[2 * k]     += bflo(vcur[k2][k]);
                acc[2 * k + 1] += bfhi(vcur[k2][k]);
            }
        if (su > 20) {          // batch B: logical slots 20..31 (k2=5,6,7)
#pragma unroll
            for (int k2 = 5; k2 < 8; ++k2) {
                u32x4 w = *(const u32x4*)(hc + (unsigned)slc[k2] * K);
#pragma unroll
                for (int k = 0; k < 4; ++k) {
                    acc[2 * k]     += bflo(w[k]);
                    acc[2 * k + 1] += bfhi(w[k]);
                }
            }
            if (su > 32) {      // batch C: physical slots 32..63 (identity)
                u16x8 s2 = *(const u16x8*)(colp + (unsigned)node * SLOTS + 32 + g * 8);
#pragma unroll
                for (int h = 0; h < 2; ++h) {
                    u32x4 x0 = *(const u32x4*)(hc + (unsigned)s2[4 * h + 0] * K);
                    u32x4 x1 = *(const u32x4*)(hc + (unsigned)s2[4 * h + 1] * K);
                    u32x4 x2 = *(const u32x4*)(hc + (unsigned)s2[4 * h + 2] * K);
                    u32x4 x3 = *(const u32x4*)(hc + (unsigned)s2[4 * h + 3] * K);
#pragma unroll
                    for (int k = 0; k < 4; ++k) {
                        acc[2 * k]     += bflo(x0[k]) + bflo(x1[k]) + bflo(x2[k]) + bflo(x3[k]);
                        acc[2 * k + 1] += bfhi(x0[k]) + bfhi(x1[k]) + bfhi(x2[k]) + bfhi(x3[k]);
                    }
                }
            }
        }

        // cross-group reduce: groups {0,1,2,3} hold partial sums of same dims
#pragma unroll
        for (int k = 0; k < 8; ++k) {
            acc[k] += __shfl_xor(acc[k], 16, 64);
            acc[k] += __shfl_xor(acc[k], 32, 64);
        }
        if (g == 0) {
            float di = rsqrtf((float)dgv[t] + 1.0f);
            const float4* bp = (const float4*)(bias + c * 8);
            float4 b0 = bp[0], b1 = bp[1];
            float bb[8] = {b0.x, b0.y, b0.z, b0.w, b1.x, b1.y, b1.z, b1.w};
            u32x4 pv;
#pragma unroll
            for (int k = 0; k < 4; ++k) {
                float o0 = fmaxf(di * acc[2 * k]     + bb[2 * k],     0.f);
                float o1 = fmaxf(di * acc[2 * k + 1] + bb[2 * k + 1], 0.f);
                pv[k] = (unsigned int)f2bf(o0) | ((unsigned int)f2bf(o1) << 16);
            }
            *(u32x4*)&As[wave * 4 + t][c * 8] = pv;   // 16B aligned
        }

        if (t < 3) {            // rotate pipeline registers
#pragma unroll
            for (int k2 = 0; k2 < 5; ++k2) vcur[k2] = vnxt[k2];
            slc = sln; sln = sl2;
        }
    }
    __syncthreads();

    // ---- gemm phase: 16 rows x M_ cols from LDS A-tile ----
    int m = lane & 15, quad = lane >> 4;
    bf16x8 afr[4];
#pragma unroll
    for (int s = 0; s < 4; ++s)
        afr[s] = *(const bf16x8*)&As[m][s * 32 + quad * 8];

    f32x4 gacc[NT];
#pragma unroll
    for (int t = 0; t < NT; ++t) { gacc[t][0] = 0.f; gacc[t][1] = 0.f; gacc[t][2] = 0.f; gacc[t][3] = 0.f; }
#pragma unroll
    for (int t = 0; t < NT; ++t) {
        int ct = wave * NT + t;     // col tile 0..M_/16-1
        const unsigned short* wp = Wt + (size_t)(ct * 16 + m) * K + quad * 8;
#pragma unroll
        for (int s = 0; s < 4; ++s) {
            bf16x8 bfr = *(const bf16x8*)(wp + s * 32);
            gacc[t] = __builtin_amdgcn_mfma_f32_16x16x32_bf16(afr[s], bfr, gacc[t], 0, 0, 0);
        }
    }

    int rowBase = tileBase + quad * 4;
    int4 dg2 = *(const int4*)(deg + rowBase);
    int dgw[4] = {dg2.x, dg2.y, dg2.z, dg2.w};
    float di[4];
#pragma unroll
    for (int i = 0; i < 4; ++i) di[i] = rsqrtf((float)dgw[i] + 1.0f);
#pragma unroll
    for (int t = 0; t < NT; ++t) {
        int ct = wave * NT + t;
#pragma unroll
        for (int i = 0; i < 4; ++i)
            Outb[(size_t)(rowBase + i) * M_ + ct * 16 + m] = f2bf(gacc[t][i] * di[i]);
    }
}

// ---- final aggregation (F=64, no relu) -> z (bf16) ----
// R17: flat depth-8 (all logical slots 0..31 unconditionally; pad rows are
// L1-hot zeros). Rare batch C only for su>32. 16 VGPR of load data.
__global__ __launch_bounds__(256, 8) void k_agg64(
        const unsigned short* __restrict__ hs, const int* __restrict__ deg,
        const unsigned short* __restrict__ colp, const float* __restrict__ bias,
        unsigned short* __restrict__ out, int n) {
    int tid = threadIdx.x;
    int wave = tid >> 6, lane = tid & 63;
    int node = blockIdx.x * 4 + wave;               // grid exactly 12500
    int g = lane >> 4, c = lane & 15;
    const unsigned short* hc = hs + c * 4;

    int degv = deg[node];
    int su = min(degv + 1, SLOTS);
    u16x8 sl = *(const u16x8*)(colp + (unsigned)node * SLOTS + g * 8);

    u32x2 vv[8];
#pragma unroll
    for (int k2 = 0; k2 < 8; ++k2)
        vv[k2] = *(const u32x2*)(hc + (unsigned)sl[k2] * 64);

    float acc[4] = {0.f, 0.f, 0.f, 0.f};
#pragma unroll
    for (int k2 = 0; k2 < 8; ++k2)
#pragma unroll
        for (int k = 0; k < 2; ++k) {
            acc[2 * k]     += bflo(vv[k2][k]);
            acc[2 * k + 1] += bfhi(vv[k2][k]);
        }
    if (su > 32) {          // batch C: physical slots 32..63
        u16x8 s2 = *(const u16x8*)(colp + (unsigned)node * SLOTS + 32 + g * 8);
#pragma unroll
        for (int h = 0; h < 2; ++h) {
            u32x2 x0 = *(const u32x2*)(hc + (unsigned)s2[4 * h + 0] * 64);
            u32x2 x1 = *(const u32x2*)(hc + (unsigned)s2[4 * h + 1] * 64);
            u32x2 x2 = *(const u32x2*)(hc + (unsigned)s2[4 * h + 2] * 64);
            u32x2 x3 = *(const u32x2*)(hc + (unsigned)s2[4 * h + 3] * 64);
#pragma unroll
            for (int k = 0; k < 2; ++k) {
                acc[2 * k]     += bflo(x0[k]) + bflo(x1[k]) + bflo(x2[k]) + bflo(x3[k]);
                acc[2 * k + 1] += bfhi(x0[k]) + bfhi(x1[k]) + bfhi(x2[k]) + bfhi(x3[k]);
            }
        }
    }
#pragma unroll
    for (int k = 0; k < 4; ++k) {
        acc[k] += __shfl_xor(acc[k], 16, 64);
        acc[k] += __shfl_xor(acc[k], 32, 64);
    }
    if (g == 0) {
        float di = rsqrtf((float)degv + 1.0f);
        float4 bb = *(const float4*)(bias + c * 4);
        u32x2 pv;
        pv[0] = (unsigned int)f2bf(di * acc[0] + bb.x) |
                ((unsigned int)f2bf(di * acc[1] + bb.y) << 16);
        pv[1] = (unsigned int)f2bf(di * acc[2] + bb.z) |
                ((unsigned int)f2bf(di * acc[3] + bb.w) << 16);
        *(u32x2*)(out + (size_t)node * 64 + c * 4) = pv;
    }
}

// ---- decode: out[e] = dot(z[ls[e]], z[ld[e]]) over 64 dims, z bf16 ----
__global__ __launch_bounds__(256) void k_decode(
        const unsigned short* __restrict__ z, const int* __restrict__ ls,
        const int* __restrict__ ld, float* __restrict__ out, int nl) {
    int tid = threadIdx.x;
    int lane = tid & 63, wave = tid >> 6;
    int g = lane >> 3, c = lane & 7;
    int e = (blockIdx.x * 4 + wave) * 4 + (g >> 1);   // grid exactly 6250
    int row = (g & 1) ? ld[e] : ls[e];
    u32x4 v = *(const u32x4*)(z + (size_t)row * 64 + c * 8);
    u32x4 w;
#pragma unroll
    for (int k = 0; k < 4; ++k) w[k] = (unsigned int)__shfl_xor((int)v[k], 8, 64);
    float p = 0.f;
#pragma unroll
    for (int k = 0; k < 4; ++k)
        p += bflo(v[k]) * bflo(w[k]) + bfhi(v[k]) * bfhi(w[k]);
    p += __shfl_xor(p, 1, 64);
    p += __shfl_xor(p, 2, 64);
    p += __shfl_xor(p, 4, 64);
    if ((lane & 15) == 0) out[e] = p;   // lane in {0,16,32,48}: g even, c==0
}

// ================= launcher =================

static inline size_t align256(size_t x) { return (x + 255) & ~(size_t)255; }

extern "C" void kernel_launch(void* const* d_in, const int* in_sizes, int n_in,
                              void* d_out, int out_size, void* d_ws, size_t ws_size,
                              hipStream_t stream) {
    const float* x  = (const float*)d_in[0];
    const int*   ei = (const int*)d_in[1];    // [2][NE]: row0=src, row1=dst
    const int*   li = (const int*)d_in[2];    // [2][NL]
    const float* W1 = (const float*)d_in[3];
    const float* b1 = (const float*)d_in[4];
    const float* W2 = (const float*)d_in[5];
    const float* b2 = (const float*)d_in[6];
    const float* W3 = (const float*)d_in[7];
    const float* b3 = (const float*)d_in[8];
    float* out = (float*)d_out;

    const int* src = ei;
    const int* dst = ei + NE;
    const int* ls = li;
    const int* ld = li + NL;

    // workspace carve-up (~43 MB)
    char* ws = (char*)d_ws;
    size_t off = 0;
    int* deg    = (int*)(ws + off); off += align256(NN * 4);
    int* cursor = (int*)(ws + off); off += align256(NB * 4);
    unsigned int* binbuf = (unsigned int*)(ws + off); off += align256((size_t)NB * BCAP * 4);
    unsigned short* colp = (unsigned short*)(ws + off); off += align256((size_t)NN * SLOTS * 2);
    unsigned short* Wtb  = (unsigned short*)(ws + off); off += align256(40960 * 2);
    // bufA: h1 (128-wide, rows 0..NN-1) + pad row at 50000.
    // h3 (64-wide) = bufA upper half; its pad row 50000 aliases bufA's.
    unsigned short* bufA = (unsigned short*)(ws + off); off += align256(((size_t)NN * 128 + 128) * 2);
    unsigned short* bufB = (unsigned short*)(ws + off); off += align256(((size_t)NN * 128 + 128) * 2);
    unsigned short* bufZ = (unsigned short*)(ws + off); off += align256((size_t)NN * 64 * 2);
    unsigned short* h3 = bufA + (size_t)25000 * 128;

    // ---- CSR build + W prep (+ zero pad rows) ----
    k_wprep<<<160, 256, 0, stream>>>(W1, W2, W3, Wtb, cursor,
                                     (unsigned int*)(bufA + (size_t)PADROW * 128),
                                     (unsigned int*)(bufB + (size_t)PADROW * 128));
    k_bin<<<391, 256, 0, stream>>>(src, dst, cursor, binbuf);
    k_csr<<<NB, 256, 0, stream>>>(binbuf, cursor, deg, colp);

    // ---- layer 1 GEMM: x -> bufA (h1 = dinv * x@W1, bf16) ----
    k_gemm1<<<782, 256, 0, stream>>>(x, Wtb, deg, bufA, NN);
    // ---- fused agg1(+b1,relu) + gemm2: bufA -> bufB (h2) ----
    k_agg_gemm<128><<<3125, 256, 0, stream>>>(bufA, deg, colp, b1, Wtb + 16384, bufB);
    // ---- fused agg2(+b2,relu) + gemm3: bufB -> h3 (64-wide) ----
    k_agg_gemm<64><<<3125, 256, 0, stream>>>(bufB, deg, colp, b2, Wtb + 32768, h3);
    // ---- agg3(+b3, no relu): h3 -> bufZ (z) ----
    k_agg64<<<12500, 256, 0, stream>>>(h3, deg, colp, b3, bufZ, NN);
    // ---- decode ----
    k_decode<<<6250, 256, 0, stream>>>(bufZ, ls, ld, out, NL);
}

// Round 6
// 247.788 us; speedup vs baseline: 1.0152x; 1.0152x over previous
//
#include <hip/hip_runtime.h>
#include <hip/hip_bf16.h>
#include <stdint.h>

// Problem constants (match reference)
#define NN 50000      // nodes
#define NE 800000     // edges
#define NL 100000     // label edges
#define SLOTS 64      // padded-CSR slots/node (incl. appended self-loop)
#define PADROW 50000  // dedicated all-zero row index in every h-buffer

// Bucketed CSR build (R7: direct scatter was line-bound)
#define NB 196        // dst-range buckets: bucket = dst >> 8 (256 nodes each)
#define BSH 8
#define BCAP 5376     // edges/bucket capacity; mean 4082 -> +20 sigma

typedef __attribute__((ext_vector_type(8))) short bf16x8;   // MFMA A/B frag
typedef __attribute__((ext_vector_type(4))) float f32x4;    // MFMA C/D frag
typedef __attribute__((ext_vector_type(4))) unsigned int u32x4;
typedef __attribute__((ext_vector_type(2))) unsigned int u32x2;
typedef __attribute__((ext_vector_type(8))) unsigned short u16x8;

__device__ __forceinline__ float asf(unsigned int u) {
    union { unsigned int i; float f; } c; c.i = u; return c.f;
}
__device__ __forceinline__ float bflo(unsigned int x) { return asf(x << 16); }
__device__ __forceinline__ float bfhi(unsigned int x) { return asf(x & 0xffff0000u); }
__device__ __forceinline__ unsigned short f2bf(float f) {
    union { float f; unsigned int i; } c; c.f = f;
    unsigned int u = c.i + (0x7fffu + ((c.i >> 16) & 1u));
    return (unsigned short)(u >> 16);
}

// async 16B global->LDS DMA: per-lane GLOBAL address, LDS dest = base+lane*16
__device__ __forceinline__ void dma16(const unsigned short* g, char* l) {
    __builtin_amdgcn_global_load_lds(
        (const __attribute__((address_space(1))) unsigned int*)g,
        (__attribute__((address_space(3))) unsigned int*)l, 16, 0, 0);
}

// ---- P0: W transpose+convert to bf16 Wt[n][k]; zero cursors + pad rows ----
__global__ void k_wprep(const float* __restrict__ W1, const float* __restrict__ W2,
                        const float* __restrict__ W3, unsigned short* __restrict__ Wt,
                        int* __restrict__ cursor, unsigned int* __restrict__ padA,
                        unsigned int* __restrict__ padB) {
    int idx = blockIdx.x * 256 + threadIdx.x;   // grid exactly 160
    if (idx < NB) cursor[idx] = 0;
    if (idx < 64) padA[idx] = 0;
    else if (idx < 128) padB[idx - 64] = 0;
    const float* W; unsigned short* O; int base, Mloc;
    if (idx < 16384)      { W = W1; O = Wt;         base = idx;         Mloc = 128; }
    else if (idx < 32768) { W = W2; O = Wt + 16384; base = idx - 16384; Mloc = 128; }
    else                  { W = W3; O = Wt + 32768; base = idx - 32768; Mloc = 64;  }
    int n = base >> 7, k = base & 127;
    O[base] = f2bf(W[k * Mloc + n]);
}

// ---- P1: bin edges by dst range (LDS histogram -> packed NT writes) ----
__global__ __launch_bounds__(256) void k_bin(
        const int* __restrict__ src, const int* __restrict__ dst,
        int* __restrict__ cursor, unsigned int* __restrict__ binbuf) {
    __shared__ int hcnt[NB];
    __shared__ int hbase[NB];
    __shared__ unsigned int epk[2048];
    int tid = threadIdx.x;
    if (tid < NB) hcnt[tid] = 0;
    __syncthreads();
    int e0 = blockIdx.x * 2048;                 // grid exactly 391
    int e1 = min(e0 + 2048, NE);
    for (int e = e0 + tid; e < e1; e += 256) {
        int d = dst[e], s = src[e];
        atomicAdd(&hcnt[d >> BSH], 1);
        epk[e - e0] = (unsigned int)s | ((unsigned int)d << 16);
    }
    __syncthreads();
    if (tid < NB) { hbase[tid] = atomicAdd(&cursor[tid], hcnt[tid]); hcnt[tid] = 0; }
    __syncthreads();
    for (int e = e0 + tid; e < e1; e += 256) {
        unsigned int pk = epk[e - e0];
        int b = (int)(pk >> 16) >> BSH;
        int p = hbase[b] + atomicAdd(&hcnt[b], 1);
        if (p < BCAP)
            __builtin_nontemporal_store(pk, &binbuf[(size_t)b * BCAP + p]);
    }
}

// ---- P2: per-bucket CSR build in LDS + coalesced flush ----
// Pad slots = PADROW (zero row -> mask-free gathers); self-loop appended at
// slot p=deg. Slots < 32 PERMUTED: logical p at physical 8*(p&3)+(p>>2), so
// lane-group g's physical [8g,8g+8): element k2 <-> logical 4*k2+g.
__global__ __launch_bounds__(256) void k_csr(
        const unsigned int* __restrict__ binbuf, const int* __restrict__ cursor,
        int* __restrict__ deg, unsigned short* __restrict__ colp) {
    __shared__ unsigned short lcol[256 * SLOTS];   // 32 KB
    __shared__ int ldeg[256];
    int tid = threadIdx.x;
    int blk = blockIdx.x;                          // grid exactly NB
    int base = blk << BSH;
    int nNodes = min(256, NN - base);
    ldeg[tid] = 0;
    const unsigned int fw = 0xC350C350u;           // 2x 50000
    u32x4 fill = {fw, fw, fw, fw};
    u32x4* lz = (u32x4*)lcol;
#pragma unroll
    for (int i = 0; i < 8; ++i) lz[i * 256 + tid] = fill;
    __syncthreads();
    int cnt = min(cursor[blk], BCAP);
    for (int e = tid; e < cnt; e += 256) {
        unsigned int pk = __builtin_nontemporal_load(&binbuf[(size_t)blk * BCAP + e]);
        int d = (int)(pk >> 16) - base;
        int p = atomicAdd(&ldeg[d], 1);
        if (p < SLOTS) {
            int pp = (p < 32) ? ((p & 3) * 8 + (p >> 2)) : p;
            lcol[d * SLOTS + pp] = (unsigned short)(pk & 0xffffu);
        }
    }
    __syncthreads();
    if (tid < nNodes) {
        int dv = ldeg[tid];
        deg[base + tid] = dv;
        if (dv < SLOTS) {                          // append self-loop slot
            int pp = (dv < 32) ? ((dv & 3) * 8 + (dv >> 2)) : dv;
            lcol[tid * SLOTS + pp] = (unsigned short)(base + tid);
        }
    }
    __syncthreads();
    u32x4* gout = (u32x4*)(colp + (size_t)base * SLOTS);
    const u32x4* lin = (const u32x4*)lcol;
    for (int i = tid; i < nNodes * 8; i += 256) gout[i] = lin[i];
}

// ---- layer-1 GEMM: x (fp32) -> bufA (h1). Rows >= NN untouched (pad!) ----
__global__ __launch_bounds__(256) void k_gemm1(
        const float* __restrict__ A, const unsigned short* __restrict__ Wt,
        const int* __restrict__ deg, unsigned short* __restrict__ Outb, int N) {
    constexpr int K = 128;
    constexpr int NT = 8;
    int tid = threadIdx.x;
    int lane = tid & 63, wave = tid >> 6;
    int m = lane & 15, quad = lane >> 4;
    int rowA = blockIdx.x * 64 + wave * 16 + m;    // grid exactly 782
    int rA = min(rowA, N - 1);

    bf16x8 afr[4];
    const float* p = A + (size_t)rA * K + quad * 8;
#pragma unroll
    for (int s = 0; s < 4; ++s) {
        float4 lo = *(const float4*)(p + s * 32);
        float4 hi = *(const float4*)(p + s * 32 + 4);
        bf16x8 r;
        r[0] = (short)f2bf(lo.x); r[1] = (short)f2bf(lo.y);
        r[2] = (short)f2bf(lo.z); r[3] = (short)f2bf(lo.w);
        r[4] = (short)f2bf(hi.x); r[5] = (short)f2bf(hi.y);
        r[6] = (short)f2bf(hi.z); r[7] = (short)f2bf(hi.w);
        afr[s] = r;
    }

    f32x4 acc[NT];
#pragma unroll
    for (int t = 0; t < NT; ++t) { acc[t][0] = 0.f; acc[t][1] = 0.f; acc[t][2] = 0.f; acc[t][3] = 0.f; }
#pragma unroll
    for (int t = 0; t < NT; ++t) {
        const unsigned short* wp = Wt + (size_t)(t * 16 + m) * K + quad * 8;
#pragma unroll
        for (int s = 0; s < 4; ++s) {
            bf16x8 bfr = *(const bf16x8*)(wp + s * 32);
            acc[t] = __builtin_amdgcn_mfma_f32_16x16x32_bf16(afr[s], bfr, acc[t], 0, 0, 0);
        }
    }

    int outRowBase = blockIdx.x * 64 + wave * 16 + quad * 4;
    float di[4];
#pragma unroll
    for (int i = 0; i < 4; ++i) di[i] = rsqrtf((float)deg[min(outRowBase + i, N - 1)] + 1.0f);
#pragma unroll
    for (int t = 0; t < NT; ++t)
#pragma unroll
        for (int i = 0; i < 4; ++i) {
            int rr = outRowBase + i;
            if (rr < N) Outb[(size_t)rr * 128 + t * 16 + m] = f2bf(acc[t][i] * di[i]);
        }
}

// ---- FUSED agg+gemm (R18: zero-register LDS-DMA gather) ----
// R14-R17 post-mortem: register-based gather MLP always loses (spill or
// occupancy cliff; allocator caps this kernel's gather at ~24 live VGPR).
// R18: gathers go global->LDS via global_load_lds (per-lane GLOBAL addr,
// LDS dest = base+lane*16; NO destination VGPRs, depth tracked by vmcnt).
// Per node: up to 8 predicated DMA instrs (4 rows each) stage ceil(su/4)*4
// slots (avg ~18.5, -23% traffic vs R16's fixed 24+) into stage[wave]
// (8KB); vmcnt(0); 8x ds_read_b128 + adds. Rare su>32 keeps register path.
// LDS 37KB/block -> 4 blocks/CU = 16 waves/CU, each with 8 loads in flight.
template <int M_>
__global__ __launch_bounds__(256, 4) void k_agg_gemm(
        const unsigned short* __restrict__ hs, const int* __restrict__ deg,
        const unsigned short* __restrict__ colp, const float* __restrict__ bias,
        const unsigned short* __restrict__ Wt, unsigned short* __restrict__ Outb) {
    constexpr int K = 128;          // agg feature width and gemm K
    constexpr int NT = M_ / 64;     // col tiles per wave: 128->2, 64->1
    __shared__ __align__(16) unsigned short As[16][136];
    __shared__ __align__(16) char stage[4][8192];   // 32 slots x 256B per wave
    int tid = threadIdx.x;
    int lane = tid & 63, wave = tid >> 6;
    int tileBase = blockIdx.x * 16;
    int g = lane >> 4, c = lane & 15;
    const unsigned short* hc = hs + c * 8;
    int nodeB = tileBase + wave * 4;

    int4 dg = *(const int4*)(deg + nodeB);         // 16B aligned
    int dgv[4] = {dg.x, dg.y, dg.z, dg.w};
    u16x8 sl4[4];
#pragma unroll
    for (int t = 0; t < 4; ++t)
        sl4[t] = *(const u16x8*)(colp + (unsigned)(nodeB + t) * SLOTS + g * 8);

    char* sb = &stage[wave][0];

    // ---- agg phase: wave aggregates rows wave*4 .. wave*4+3 ----
#pragma unroll
    for (int t = 0; t < 4; ++t) {
        int node = nodeB + t;
        int su = min(dgv[t] + 1, SLOTS);           // slots incl. self

        // issue DMAs: instr j stages logical slots 4j..4j+3 (4 rows x 256B).
        // lane l=(g*16+c): global addr = row sl4[t][j] (uniform in group),
        // chunk c*16B; HW writes LDS at sb+j*1024 + l*16 = g*256 + c*16.
#pragma unroll
        for (int j = 0; j < 8; ++j)
            if (4 * j < su)                        // wave-uniform predicate
                dma16(hc + (unsigned)sl4[t][j] * K, sb + j * 1024);

        float acc[8];
#pragma unroll
        for (int k = 0; k < 8; ++k) acc[k] = 0.f;

        if (su > 32) {      // rare tail: physical slots 32..63, register path
            u16x8 s2 = *(const u16x8*)(colp + (unsigned)node * SLOTS + 32 + g * 8);
#pragma unroll
            for (int h = 0; h < 8; ++h) {
                u32x4 x = *(const u32x4*)(hc + (unsigned)s2[h] * K);
#pragma unroll
                for (int k = 0; k < 4; ++k) {
                    acc[2 * k]     += bflo(x[k]);
                    acc[2 * k + 1] += bfhi(x[k]);
                }
            }
        }

        asm volatile("s_waitcnt vmcnt(0)" ::: "memory");

#pragma unroll
        for (int j = 0; j < 8; ++j) {
            if (4 * j < su) {
                u32x4 v = *(const u32x4*)(sb + j * 1024 + g * 256 + c * 16);
#pragma unroll
                for (int k = 0; k < 4; ++k) {
                    acc[2 * k]     += bflo(v[k]);
                    acc[2 * k + 1] += bfhi(v[k]);
                }
            }
        }

        // cross-group reduce: groups {0,1,2,3} hold partial sums of same dims
#pragma unroll
        for (int k = 0; k < 8; ++k) {
            acc[k] += __shfl_xor(acc[k], 16, 64);
            acc[k] += __shfl_xor(acc[k], 32, 64);
        }
        if (g == 0) {
            float di = rsqrtf((float)dgv[t] + 1.0f);
            const float4* bp = (const float4*)(bias + c * 8);
            float4 b0 = bp[0], b1 = bp[1];
            float bb[8] = {b0.x, b0.y, b0.z, b0.w, b1.x, b1.y, b1.z, b1.w};
            u32x4 pv;
#pragma unroll
            for (int k = 0; k < 4; ++k) {
                float o0 = fmaxf(di * acc[2 * k]     + bb[2 * k],     0.f);
                float o1 = fmaxf(di * acc[2 * k + 1] + bb[2 * k + 1], 0.f);
                pv[k] = (unsigned int)f2bf(o0) | ((unsigned int)f2bf(o1) << 16);
            }
            *(u32x4*)&As[wave * 4 + t][c * 8] = pv;   // 16B aligned
        }
    }
    __syncthreads();

    // ---- gemm phase: 16 rows x M_ cols from LDS A-tile ----
    int m = lane & 15, quad = lane >> 4;
    bf16x8 afr[4];
#pragma unroll
    for (int s = 0; s < 4; ++s)
        afr[s] = *(const bf16x8*)&As[m][s * 32 + quad * 8];

    f32x4 gacc[NT];
#pragma unroll
    for (int t = 0; t < NT; ++t) { gacc[t][0] = 0.f; gacc[t][1] = 0.f; gacc[t][2] = 0.f; gacc[t][3] = 0.f; }
#pragma unroll
    for (int t = 0; t < NT; ++t) {
        int ct = wave * NT + t;     // col tile 0..M_/16-1
        const unsigned short* wp = Wt + (size_t)(ct * 16 + m) * K + quad * 8;
#pragma unroll
        for (int s = 0; s < 4; ++s) {
            bf16x8 bfr = *(const bf16x8*)(wp + s * 32);
            gacc[t] = __builtin_amdgcn_mfma_f32_16x16x32_bf16(afr[s], bfr, gacc[t], 0, 0, 0);
        }
    }

    int rowBase = tileBase + quad * 4;
    int4 dg2 = *(const int4*)(deg + rowBase);
    int dgw[4] = {dg2.x, dg2.y, dg2.z, dg2.w};
    float di[4];
#pragma unroll
    for (int i = 0; i < 4; ++i) di[i] = rsqrtf((float)dgw[i] + 1.0f);
#pragma unroll
    for (int t = 0; t < NT; ++t) {
        int ct = wave * NT + t;
#pragma unroll
        for (int i = 0; i < 4; ++i)
            Outb[(size_t)(rowBase + i) * M_ + ct * 16 + m] = f2bf(gacc[t][i] * di[i]);
    }
}

// ---- final aggregation (F=64, no relu) -> z (bf16) ----
// R16 version (proven in the 232us build): depth-6 mask-free + cond B/C.
__global__ __launch_bounds__(256, 8) void k_agg64(
        const unsigned short* __restrict__ hs, const int* __restrict__ deg,
        const unsigned short* __restrict__ colp, const float* __restrict__ bias,
        unsigned short* __restrict__ out, int n) {
    int tid = threadIdx.x;
    int wave = tid >> 6, lane = tid & 63;
    int node = blockIdx.x * 4 + wave;               // grid exactly 12500
    int g = lane >> 4, c = lane & 15;
    const unsigned short* hc = hs + c * 4;

    int degv = deg[node];
    int su = min(degv + 1, SLOTS);
    u16x8 sl = *(const u16x8*)(colp + (unsigned)node * SLOTS + g * 8);

    u32x2 vv[6];
#pragma unroll
    for (int k2 = 0; k2 < 6; ++k2)
        vv[k2] = *(const u32x2*)(hc + (unsigned)sl[k2] * 64);

    float acc[4] = {0.f, 0.f, 0.f, 0.f};
#pragma unroll
    for (int k2 = 0; k2 < 6; ++k2)
#pragma unroll
        for (int k = 0; k < 2; ++k) {
            acc[2 * k]     += bflo(vv[k2][k]);
            acc[2 * k + 1] += bfhi(vv[k2][k]);
        }
    if (su > 24) {              // batch B: logical slots 24..31
        u32x2 w0 = *(const u32x2*)(hc + (unsigned)sl[6] * 64);
        u32x2 w1 = *(const u32x2*)(hc + (unsigned)sl[7] * 64);
#pragma unroll
        for (int k = 0; k < 2; ++k) {
            acc[2 * k]     += bflo(w0[k]) + bflo(w1[k]);
            acc[2 * k + 1] += bfhi(w0[k]) + bfhi(w1[k]);
        }
        if (su > 32) {          // batch C: physical slots 32..63
            u16x8 s2 = *(const u16x8*)(colp + (unsigned)node * SLOTS + 32 + g * 8);
#pragma unroll
            for (int h = 0; h < 2; ++h) {
                u32x2 x0 = *(const u32x2*)(hc + (unsigned)s2[4 * h + 0] * 64);
                u32x2 x1 = *(const u32x2*)(hc + (unsigned)s2[4 * h + 1] * 64);
                u32x2 x2 = *(const u32x2*)(hc + (unsigned)s2[4 * h + 2] * 64);
                u32x2 x3 = *(const u32x2*)(hc + (unsigned)s2[4 * h + 3] * 64);
#pragma unroll
                for (int k = 0; k < 2; ++k) {
                    acc[2 * k]     += bflo(x0[k]) + bflo(x1[k]) + bflo(x2[k]) + bflo(x3[k]);
                    acc[2 * k + 1] += bfhi(x0[k]) + bfhi(x1[k]) + bfhi(x2[k]) + bfhi(x3[k]);
                }
            }
        }
    }
#pragma unroll
    for (int k = 0; k < 4; ++k) {
        acc[k] += __shfl_xor(acc[k], 16, 64);
        acc[k] += __shfl_xor(acc[k], 32, 64);
    }
    if (g == 0) {
        float di = rsqrtf((float)degv + 1.0f);
        float4 bb = *(const float4*)(bias + c * 4);
        u32x2 pv;
        pv[0] = (unsigned int)f2bf(di * acc[0] + bb.x) |
                ((unsigned int)f2bf(di * acc[1] + bb.y) << 16);
        pv[1] = (unsigned int)f2bf(di * acc[2] + bb.z) |
                ((unsigned int)f2bf(di * acc[3] + bb.w) << 16);
        *(u32x2*)(out + (size_t)node * 64 + c * 4) = pv;
    }
}

// ---- decode: out[e] = dot(z[ls[e]], z[ld[e]]) over 64 dims, z bf16 ----
__global__ __launch_bounds__(256) void k_decode(
        const unsigned short* __restrict__ z, const int* __restrict__ ls,
        const int* __restrict__ ld, float* __restrict__ out, int nl) {
    int tid = threadIdx.x;
    int lane = tid & 63, wave = tid >> 6;
    int g = lane >> 3, c = lane & 7;
    int e = (blockIdx.x * 4 + wave) * 4 + (g >> 1);   // grid exactly 6250
    int row = (g & 1) ? ld[e] : ls[e];
    u32x4 v = *(const u32x4*)(z + (size_t)row * 64 + c * 8);
    u32x4 w;
#pragma unroll
    for (int k = 0; k < 4; ++k) w[k] = (unsigned int)__shfl_xor((int)v[k], 8, 64);
    float p = 0.f;
#pragma unroll
    for (int k = 0; k < 4; ++k)
        p += bflo(v[k]) * bflo(w[k]) + bfhi(v[k]) * bfhi(w[k]);
    p += __shfl_xor(p, 1, 64);
    p += __shfl_xor(p, 2, 64);
    p += __shfl_xor(p, 4, 64);
    if ((lane & 15) == 0) out[e] = p;   // lane in {0,16,32,48}: g even, c==0
}

// ================= launcher =================

static inline size_t align256(size_t x) { return (x + 255) & ~(size_t)255; }

extern "C" void kernel_launch(void* const* d_in, const int* in_sizes, int n_in,
                              void* d_out, int out_size, void* d_ws, size_t ws_size,
                              hipStream_t stream) {
    const float* x  = (const float*)d_in[0];
    const int*   ei = (const int*)d_in[1];    // [2][NE]: row0=src, row1=dst
    const int*   li = (const int*)d_in[2];    // [2][NL]
    const float* W1 = (const float*)d_in[3];
    const float* b1 = (const float*)d_in[4];
    const float* W2 = (const float*)d_in[5];
    const float* b2 = (const float*)d_in[6];
    const float* W3 = (const float*)d_in[7];
    const float* b3 = (const float*)d_in[8];
    float* out = (float*)d_out;

    const int* src = ei;
    const int* dst = ei + NE;
    const int* ls = li;
    const int* ld = li + NL;

    // workspace carve-up (~43 MB)
    char* ws = (char*)d_ws;
    size_t off = 0;
    int* deg    = (int*)(ws + off); off += align256(NN * 4);
    int* cursor = (int*)(ws + off); off += align256(NB * 4);
    unsigned int* binbuf = (unsigned int*)(ws + off); off += align256((size_t)NB * BCAP * 4);
    unsigned short* colp = (unsigned short*)(ws + off); off += align256((size_t)NN * SLOTS * 2);
    unsigned short* Wtb  = (unsigned short*)(ws + off); off += align256(40960 * 2);
    // bufA: h1 (128-wide, rows 0..NN-1) + pad row at 50000.
    // h3 (64-wide) = bufA upper half; its pad row 50000 aliases bufA's.
    unsigned short* bufA = (unsigned short*)(ws + off); off += align256(((size_t)NN * 128 + 128) * 2);
    unsigned short* bufB = (unsigned short*)(ws + off); off += align256(((size_t)NN * 128 + 128) * 2);
    unsigned short* bufZ = (unsigned short*)(ws + off); off += align256((size_t)NN * 64 * 2);
    unsigned short* h3 = bufA + (size_t)25000 * 128;

    // ---- CSR build + W prep (+ zero pad rows) ----
    k_wprep<<<160, 256, 0, stream>>>(W1, W2, W3, Wtb, cursor,
                                     (unsigned int*)(bufA + (size_t)PADROW * 128),
                                     (unsigned int*)(bufB + (size_t)PADROW * 128));
    k_bin<<<391, 256, 0, stream>>>(src, dst, cursor, binbuf);
    k_csr<<<NB, 256, 0, stream>>>(binbuf, cursor, deg, colp);

    // ---- layer 1 GEMM: x -> bufA (h1 = dinv * x@W1, bf16) ----
    k_gemm1<<<782, 256, 0, stream>>>(x, Wtb, deg, bufA, NN);
    // ---- fused agg1(+b1,relu) + gemm2: bufA -> bufB (h2) ----
    k_agg_gemm<128><<<3125, 256, 0, stream>>>(bufA, deg, colp, b1, Wtb + 16384, bufB);
    // ---- fused agg2(+b2,relu) + gemm3: bufB -> h3 (64-wide) ----
    k_agg_gemm<64><<<3125, 256, 0, stream>>>(bufB, deg, colp, b2, Wtb + 32768, h3);
    // ---- agg3(+b3, no relu): h3 -> bufZ (z) ----
    k_agg64<<<12500, 256, 0, stream>>>(h3, deg, colp, b3, bufZ, NN);
    // ---- decode ----
    k_decode<<<6250, 256, 0, stream>>>(bufZ, ls, ld, out, NL);
}

// Round 7
// 237.000 us; speedup vs baseline: 1.0614x; 1.0455x over previous
//
#include <hip/hip_runtime.h>
#include <hip/hip_bf16.h>
#include <stdint.h>

// Problem constants (match reference)
#define NN 50000      // nodes
#define NE 800000     // edges
#define NL 100000     // label edges
#define SLOTS 64      // padded-CSR slots/node (incl. appended self-loop)
#define PADROW 50000  // dedicated all-zero row index in every h-buffer

// Bucketed CSR build (R7: direct scatter was line-bound)
#define NB 196        // dst-range buckets: bucket = dst >> 8 (256 nodes each)
#define BSH 8
#define BCAP 5376     // edges/bucket capacity; mean 4082 -> +20 sigma

typedef __attribute__((ext_vector_type(8))) short bf16x8;   // MFMA A/B frag
typedef __attribute__((ext_vector_type(4))) float f32x4;    // MFMA C/D frag
typedef __attribute__((ext_vector_type(4))) unsigned int u32x4;
typedef __attribute__((ext_vector_type(2))) unsigned int u32x2;
typedef __attribute__((ext_vector_type(8))) unsigned short u16x8;

__device__ __forceinline__ float asf(unsigned int u) {
    union { unsigned int i; float f; } c; c.i = u; return c.f;
}
__device__ __forceinline__ float bflo(unsigned int x) { return asf(x << 16); }
__device__ __forceinline__ float bfhi(unsigned int x) { return asf(x & 0xffff0000u); }
__device__ __forceinline__ unsigned short f2bf(float f) {
    union { float f; unsigned int i; } c; c.f = f;
    unsigned int u = c.i + (0x7fffu + ((c.i >> 16) & 1u));
    return (unsigned short)(u >> 16);
}

// async 16B global->LDS DMA: per-lane GLOBAL address, LDS dest = base+lane*16
__device__ __forceinline__ void dma16(const unsigned short* g, char* l) {
    __builtin_amdgcn_global_load_lds(
        (const __attribute__((address_space(1))) unsigned int*)g,
        (__attribute__((address_space(3))) unsigned int*)l, 16, 0, 0);
}

// ---- P0: W transpose+convert to bf16 Wt[n][k]; zero cursors + pad rows ----
__global__ void k_wprep(const float* __restrict__ W1, const float* __restrict__ W2,
                        const float* __restrict__ W3, unsigned short* __restrict__ Wt,
                        int* __restrict__ cursor, unsigned int* __restrict__ padA,
                        unsigned int* __restrict__ padB) {
    int idx = blockIdx.x * 256 + threadIdx.x;   // grid exactly 160
    if (idx < NB) cursor[idx] = 0;
    if (idx < 64) padA[idx] = 0;
    else if (idx < 128) padB[idx - 64] = 0;
    const float* W; unsigned short* O; int base, Mloc;
    if (idx < 16384)      { W = W1; O = Wt;         base = idx;         Mloc = 128; }
    else if (idx < 32768) { W = W2; O = Wt + 16384; base = idx - 16384; Mloc = 128; }
    else                  { W = W3; O = Wt + 32768; base = idx - 32768; Mloc = 64;  }
    int n = base >> 7, k = base & 127;
    O[base] = f2bf(W[k * Mloc + n]);
}

// ---- P1: bin edges by dst range (LDS histogram -> packed NT writes) ----
__global__ __launch_bounds__(256) void k_bin(
        const int* __restrict__ src, const int* __restrict__ dst,
        int* __restrict__ cursor, unsigned int* __restrict__ binbuf) {
    __shared__ int hcnt[NB];
    __shared__ int hbase[NB];
    __shared__ unsigned int epk[2048];
    int tid = threadIdx.x;
    if (tid < NB) hcnt[tid] = 0;
    __syncthreads();
    int e0 = blockIdx.x * 2048;                 // grid exactly 391
    int e1 = min(e0 + 2048, NE);
    for (int e = e0 + tid; e < e1; e += 256) {
        int d = dst[e], s = src[e];
        atomicAdd(&hcnt[d >> BSH], 1);
        epk[e - e0] = (unsigned int)s | ((unsigned int)d << 16);
    }
    __syncthreads();
    if (tid < NB) { hbase[tid] = atomicAdd(&cursor[tid], hcnt[tid]); hcnt[tid] = 0; }
    __syncthreads();
    for (int e = e0 + tid; e < e1; e += 256) {
        unsigned int pk = epk[e - e0];
        int b = (int)(pk >> 16) >> BSH;
        int p = hbase[b] + atomicAdd(&hcnt[b], 1);
        if (p < BCAP)
            __builtin_nontemporal_store(pk, &binbuf[(size_t)b * BCAP + p]);
    }
}

// ---- P2: per-bucket CSR build in LDS + coalesced flush ----
// Pad slots = PADROW (zero row -> mask-free gathers); self-loop appended at
// slot p=deg. Slots < 32 PERMUTED: logical p at physical 8*(p&3)+(p>>2), so
// lane-group g's physical [8g,8g+8): element k2 <-> logical 4*k2+g.
__global__ __launch_bounds__(256) void k_csr(
        const unsigned int* __restrict__ binbuf, const int* __restrict__ cursor,
        int* __restrict__ deg, unsigned short* __restrict__ colp) {
    __shared__ unsigned short lcol[256 * SLOTS];   // 32 KB
    __shared__ int ldeg[256];
    int tid = threadIdx.x;
    int blk = blockIdx.x;                          // grid exactly NB
    int base = blk << BSH;
    int nNodes = min(256, NN - base);
    ldeg[tid] = 0;
    const unsigned int fw = 0xC350C350u;           // 2x 50000
    u32x4 fill = {fw, fw, fw, fw};
    u32x4* lz = (u32x4*)lcol;
#pragma unroll
    for (int i = 0; i < 8; ++i) lz[i * 256 + tid] = fill;
    __syncthreads();
    int cnt = min(cursor[blk], BCAP);
    for (int e = tid; e < cnt; e += 256) {
        unsigned int pk = __builtin_nontemporal_load(&binbuf[(size_t)blk * BCAP + e]);
        int d = (int)(pk >> 16) - base;
        int p = atomicAdd(&ldeg[d], 1);
        if (p < SLOTS) {
            int pp = (p < 32) ? ((p & 3) * 8 + (p >> 2)) : p;
            lcol[d * SLOTS + pp] = (unsigned short)(pk & 0xffffu);
        }
    }
    __syncthreads();
    if (tid < nNodes) {
        int dv = ldeg[tid];
        deg[base + tid] = dv;
        if (dv < SLOTS) {                          // append self-loop slot
            int pp = (dv < 32) ? ((dv & 3) * 8 + (dv >> 2)) : dv;
            lcol[tid * SLOTS + pp] = (unsigned short)(base + tid);
        }
    }
    __syncthreads();
    u32x4* gout = (u32x4*)(colp + (size_t)base * SLOTS);
    const u32x4* lin = (const u32x4*)lcol;
    for (int i = tid; i < nNodes * 8; i += 256) gout[i] = lin[i];
}

// ---- layer-1 GEMM: x (fp32) -> bufA (h1). Rows >= NN untouched (pad!) ----
__global__ __launch_bounds__(256) void k_gemm1(
        const float* __restrict__ A, const unsigned short* __restrict__ Wt,
        const int* __restrict__ deg, unsigned short* __restrict__ Outb, int N) {
    constexpr int K = 128;
    constexpr int NT = 8;
    int tid = threadIdx.x;
    int lane = tid & 63, wave = tid >> 6;
    int m = lane & 15, quad = lane >> 4;
    int rowA = blockIdx.x * 64 + wave * 16 + m;    // grid exactly 782
    int rA = min(rowA, N - 1);

    bf16x8 afr[4];
    const float* p = A + (size_t)rA * K + quad * 8;
#pragma unroll
    for (int s = 0; s < 4; ++s) {
        float4 lo = *(const float4*)(p + s * 32);
        float4 hi = *(const float4*)(p + s * 32 + 4);
        bf16x8 r;
        r[0] = (short)f2bf(lo.x); r[1] = (short)f2bf(lo.y);
        r[2] = (short)f2bf(lo.z); r[3] = (short)f2bf(lo.w);
        r[4] = (short)f2bf(hi.x); r[5] = (short)f2bf(hi.y);
        r[6] = (short)f2bf(hi.z); r[7] = (short)f2bf(hi.w);
        afr[s] = r;
    }

    f32x4 acc[NT];
#pragma unroll
    for (int t = 0; t < NT; ++t) { acc[t][0] = 0.f; acc[t][1] = 0.f; acc[t][2] = 0.f; acc[t][3] = 0.f; }
#pragma unroll
    for (int t = 0; t < NT; ++t) {
        const unsigned short* wp = Wt + (size_t)(t * 16 + m) * K + quad * 8;
#pragma unroll
        for (int s = 0; s < 4; ++s) {
            bf16x8 bfr = *(const bf16x8*)(wp + s * 32);
            acc[t] = __builtin_amdgcn_mfma_f32_16x16x32_bf16(afr[s], bfr, acc[t], 0, 0, 0);
        }
    }

    int outRowBase = blockIdx.x * 64 + wave * 16 + quad * 4;
    float di[4];
#pragma unroll
    for (int i = 0; i < 4; ++i) di[i] = rsqrtf((float)deg[min(outRowBase + i, N - 1)] + 1.0f);
#pragma unroll
    for (int t = 0; t < NT; ++t)
#pragma unroll
        for (int i = 0; i < 4; ++i) {
            int rr = outRowBase + i;
            if (rr < N) Outb[(size_t)rr * 128 + t * 16 + m] = f2bf(acc[t][i] * di[i]);
        }
}

// ---- FUSED agg+gemm (R19: double-buffered counted-vmcnt DMA pipeline) ----
// R18 post-mortem: vmcnt(0) per node = zero cross-node overlap (57.6us).
// R19: fixed 6 DMAs/node (24 slots; su<=24 P=.97; pads hit L1-hot zero row)
// -> compile-time vmcnt immediates. Prologue stages nodes 0,1; iter t waits
// vmcnt(6) (drain node t ONLY -- never 0 until t=3), accumulates buf[t&1],
// re-issues node t+2 into it. Steady state: 12 loads in flight per wave,
// continuously. Loop is VMEM-clean (bias preloaded) so immediates stay
// exact; sched_barrier(0) pins issue after buffer reads. Rare su>24 tail
// uses register loads (compiler drain over-synchronizes: correct, 3%).
// LDS 53.5KB/block -> 3 blocks/CU = 12 waves/CU.
template <int M_>
__global__ __launch_bounds__(256) void k_agg_gemm(
        const unsigned short* __restrict__ hs, const int* __restrict__ deg,
        const unsigned short* __restrict__ colp, const float* __restrict__ bias,
        const unsigned short* __restrict__ Wt, unsigned short* __restrict__ Outb) {
    constexpr int K = 128;          // agg feature width and gemm K
    constexpr int NT = M_ / 64;     // col tiles per wave: 128->2, 64->1
    __shared__ __align__(16) unsigned short As[16][136];
    __shared__ __align__(16) char stage[4][2][6144];   // 24 slots x 256B x dbuf
    int tid = threadIdx.x;
    int lane = tid & 63, wave = tid >> 6;
    int tileBase = blockIdx.x * 16;
    int g = lane >> 4, c = lane & 15;
    const unsigned short* hc = hs + c * 8;
    int nodeB = tileBase + wave * 4;

    int4 dg = *(const int4*)(deg + nodeB);         // 16B aligned
    int dgv[4] = {dg.x, dg.y, dg.z, dg.w};
    u16x8 sl4[4];
#pragma unroll
    for (int t = 0; t < 4; ++t)
        sl4[t] = *(const u16x8*)(colp + (unsigned)(nodeB + t) * SLOTS + g * 8);

    // bias slice preloaded: keeps the steady-state loop VMEM-clean so the
    // counted vmcnt immediates are exact.
    float bb[8];
    {
        const float4* bp = (const float4*)(bias + c * 8);
        float4 b0 = bp[0], b1 = bp[1];
        bb[0] = b0.x; bb[1] = b0.y; bb[2] = b0.z; bb[3] = b0.w;
        bb[4] = b1.x; bb[5] = b1.y; bb[6] = b1.z; bb[7] = b1.w;
    }

    // prologue: stage nodes 0 and 1
#pragma unroll
    for (int j = 0; j < 6; ++j)
        dma16(hc + (unsigned)sl4[0][j] * K, &stage[wave][0][j * 1024]);
#pragma unroll
    for (int j = 0; j < 6; ++j)
        dma16(hc + (unsigned)sl4[1][j] * K, &stage[wave][1][j * 1024]);

    // ---- agg phase: wave aggregates rows wave*4 .. wave*4+3 ----
#pragma unroll
    for (int t = 0; t < 4; ++t) {
        int node = nodeB + t;
        int su = min(dgv[t] + 1, SLOTS);           // slots incl. self

        if (t < 3) asm volatile("s_waitcnt vmcnt(6)" ::: "memory");
        else       asm volatile("s_waitcnt vmcnt(0)" ::: "memory");
        __builtin_amdgcn_sched_barrier(0);

        const char* sb = &stage[wave][t & 1][0];
        float acc[8];
#pragma unroll
        for (int k = 0; k < 8; ++k) acc[k] = 0.f;
#pragma unroll
        for (int j = 0; j < 6; ++j) {
            u32x4 v = *(const u32x4*)(sb + j * 1024 + g * 256 + c * 16);
#pragma unroll
            for (int k = 0; k < 4; ++k) {
                acc[2 * k]     += bflo(v[k]);
                acc[2 * k + 1] += bfhi(v[k]);
            }
        }

        if (su > 24) {      // rare tail: logical slots 24..31, register path
            u32x4 w0 = *(const u32x4*)(hc + (unsigned)sl4[t][6] * K);
            u32x4 w1 = *(const u32x4*)(hc + (unsigned)sl4[t][7] * K);
#pragma unroll
            for (int k = 0; k < 4; ++k) {
                acc[2 * k]     += bflo(w0[k]) + bflo(w1[k]);
                acc[2 * k + 1] += bfhi(w0[k]) + bfhi(w1[k]);
            }
            if (su > 32) {  // ultra-rare: physical slots 32..63 (identity)
                u16x8 s2 = *(const u16x8*)(colp + (unsigned)node * SLOTS + 32 + g * 8);
#pragma unroll
                for (int h = 0; h < 8; ++h) {
                    u32x4 x = *(const u32x4*)(hc + (unsigned)s2[h] * K);
#pragma unroll
                    for (int k = 0; k < 4; ++k) {
                        acc[2 * k]     += bflo(x[k]);
                        acc[2 * k + 1] += bfhi(x[k]);
                    }
                }
            }
        }

        // re-issue this buffer for node t+2 (reads above are complete: the
        // adds consumed them; sched_barrier pins ordering)
        __builtin_amdgcn_sched_barrier(0);
        if (t < 2) {
#pragma unroll
            for (int j = 0; j < 6; ++j)
                dma16(hc + (unsigned)sl4[t + 2][j] * K,
                      &stage[wave][t & 1][j * 1024]);
        }

        // cross-group reduce (overlaps the just-issued DMAs)
#pragma unroll
        for (int k = 0; k < 8; ++k) {
            acc[k] += __shfl_xor(acc[k], 16, 64);
            acc[k] += __shfl_xor(acc[k], 32, 64);
        }
        if (g == 0) {
            float di = rsqrtf((float)dgv[t] + 1.0f);
            u32x4 pv;
#pragma unroll
            for (int k = 0; k < 4; ++k) {
                float o0 = fmaxf(di * acc[2 * k]     + bb[2 * k],     0.f);
                float o1 = fmaxf(di * acc[2 * k + 1] + bb[2 * k + 1], 0.f);
                pv[k] = (unsigned int)f2bf(o0) | ((unsigned int)f2bf(o1) << 16);
            }
            *(u32x4*)&As[wave * 4 + t][c * 8] = pv;   // 16B aligned
        }
    }
    __syncthreads();

    // ---- gemm phase: 16 rows x M_ cols from LDS A-tile ----
    int m = lane & 15, quad = lane >> 4;
    bf16x8 afr[4];
#pragma unroll
    for (int s = 0; s < 4; ++s)
        afr[s] = *(const bf16x8*)&As[m][s * 32 + quad * 8];

    f32x4 gacc[NT];
#pragma unroll
    for (int t = 0; t < NT; ++t) { gacc[t][0] = 0.f; gacc[t][1] = 0.f; gacc[t][2] = 0.f; gacc[t][3] = 0.f; }
#pragma unroll
    for (int t = 0; t < NT; ++t) {
        int ct = wave * NT + t;     // col tile 0..M_/16-1
        const unsigned short* wp = Wt + (size_t)(ct * 16 + m) * K + quad * 8;
#pragma unroll
        for (int s = 0; s < 4; ++s) {
            bf16x8 bfr = *(const bf16x8*)(wp + s * 32);
            gacc[t] = __builtin_amdgcn_mfma_f32_16x16x32_bf16(afr[s], bfr, gacc[t], 0, 0, 0);
        }
    }

    int rowBase = tileBase + quad * 4;
    int4 dg2 = *(const int4*)(deg + rowBase);
    int dgw[4] = {dg2.x, dg2.y, dg2.z, dg2.w};
    float di[4];
#pragma unroll
    for (int i = 0; i < 4; ++i) di[i] = rsqrtf((float)dgw[i] + 1.0f);
#pragma unroll
    for (int t = 0; t < NT; ++t) {
        int ct = wave * NT + t;
#pragma unroll
        for (int i = 0; i < 4; ++i)
            Outb[(size_t)(rowBase + i) * M_ + ct * 16 + m] = f2bf(gacc[t][i] * di[i]);
    }
}

// ---- final aggregation (F=64, no relu) -> z (bf16) ----
// R16 version (proven): depth-6 mask-free + cond B/C.
__global__ __launch_bounds__(256, 8) void k_agg64(
        const unsigned short* __restrict__ hs, const int* __restrict__ deg,
        const unsigned short* __restrict__ colp, const float* __restrict__ bias,
        unsigned short* __restrict__ out, int n) {
    int tid = threadIdx.x;
    int wave = tid >> 6, lane = tid & 63;
    int node = blockIdx.x * 4 + wave;               // grid exactly 12500
    int g = lane >> 4, c = lane & 15;
    const unsigned short* hc = hs + c * 4;

    int degv = deg[node];
    int su = min(degv + 1, SLOTS);
    u16x8 sl = *(const u16x8*)(colp + (unsigned)node * SLOTS + g * 8);

    u32x2 vv[6];
#pragma unroll
    for (int k2 = 0; k2 < 6; ++k2)
        vv[k2] = *(const u32x2*)(hc + (unsigned)sl[k2] * 64);

    float acc[4] = {0.f, 0.f, 0.f, 0.f};
#pragma unroll
    for (int k2 = 0; k2 < 6; ++k2)
#pragma unroll
        for (int k = 0; k < 2; ++k) {
            acc[2 * k]     += bflo(vv[k2][k]);
            acc[2 * k + 1] += bfhi(vv[k2][k]);
        }
    if (su > 24) {              // batch B: logical slots 24..31
        u32x2 w0 = *(const u32x2*)(hc + (unsigned)sl[6] * 64);
        u32x2 w1 = *(const u32x2*)(hc + (unsigned)sl[7] * 64);
#pragma unroll
        for (int k = 0; k < 2; ++k) {
            acc[2 * k]     += bflo(w0[k]) + bflo(w1[k]);
            acc[2 * k + 1] += bfhi(w0[k]) + bfhi(w1[k]);
        }
        if (su > 32) {          // batch C: physical slots 32..63
            u16x8 s2 = *(const u16x8*)(colp + (unsigned)node * SLOTS + 32 + g * 8);
#pragma unroll
            for (int h = 0; h < 2; ++h) {
                u32x2 x0 = *(const u32x2*)(hc + (unsigned)s2[4 * h + 0] * 64);
                u32x2 x1 = *(const u32x2*)(hc + (unsigned)s2[4 * h + 1] * 64);
                u32x2 x2 = *(const u32x2*)(hc + (unsigned)s2[4 * h + 2] * 64);
                u32x2 x3 = *(const u32x2*)(hc + (unsigned)s2[4 * h + 3] * 64);
#pragma unroll
                for (int k = 0; k < 2; ++k) {
                    acc[2 * k]     += bflo(x0[k]) + bflo(x1[k]) + bflo(x2[k]) + bflo(x3[k]);
                    acc[2 * k + 1] += bfhi(x0[k]) + bfhi(x1[k]) + bfhi(x2[k]) + bfhi(x3[k]);
                }
            }
        }
    }
#pragma unroll
    for (int k = 0; k < 4; ++k) {
        acc[k] += __shfl_xor(acc[k], 16, 64);
        acc[k] += __shfl_xor(acc[k], 32, 64);
    }
    if (g == 0) {
        float di = rsqrtf((float)degv + 1.0f);
        float4 bb = *(const float4*)(bias + c * 4);
        u32x2 pv;
        pv[0] = (unsigned int)f2bf(di * acc[0] + bb.x) |
                ((unsigned int)f2bf(di * acc[1] + bb.y) << 16);
        pv[1] = (unsigned int)f2bf(di * acc[2] + bb.z) |
                ((unsigned int)f2bf(di * acc[3] + bb.w) << 16);
        *(u32x2*)(out + (size_t)node * 64 + c * 4) = pv;
    }
}

// ---- decode: out[e] = dot(z[ls[e]], z[ld[e]]) over 64 dims, z bf16 ----
__global__ __launch_bounds__(256) void k_decode(
        const unsigned short* __restrict__ z, const int* __restrict__ ls,
        const int* __restrict__ ld, float* __restrict__ out, int nl) {
    int tid = threadIdx.x;
    int lane = tid & 63, wave = tid >> 6;
    int g = lane >> 3, c = lane & 7;
    int e = (blockIdx.x * 4 + wave) * 4 + (g >> 1);   // grid exactly 6250
    int row = (g & 1) ? ld[e] : ls[e];
    u32x4 v = *(const u32x4*)(z + (size_t)row * 64 + c * 8);
    u32x4 w;
#pragma unroll
    for (int k = 0; k < 4; ++k) w[k] = (unsigned int)__shfl_xor((int)v[k], 8, 64);
    float p = 0.f;
#pragma unroll
    for (int k = 0; k < 4; ++k)
        p += bflo(v[k]) * bflo(w[k]) + bfhi(v[k]) * bfhi(w[k]);
    p += __shfl_xor(p, 1, 64);
    p += __shfl_xor(p, 2, 64);
    p += __shfl_xor(p, 4, 64);
    if ((lane & 15) == 0) out[e] = p;   // lane in {0,16,32,48}: g even, c==0
}

// ================= launcher =================

static inline size_t align256(size_t x) { return (x + 255) & ~(size_t)255; }

extern "C" void kernel_launch(void* const* d_in, const int* in_sizes, int n_in,
                              void* d_out, int out_size, void* d_ws, size_t ws_size,
                              hipStream_t stream) {
    const float* x  = (const float*)d_in[0];
    const int*   ei = (const int*)d_in[1];    // [2][NE]: row0=src, row1=dst
    const int*   li = (const int*)d_in[2];    // [2][NL]
    const float* W1 = (const float*)d_in[3];
    const float* b1 = (const float*)d_in[4];
    const float* W2 = (const float*)d_in[5];
    const float* b2 = (const float*)d_in[6];
    const float* W3 = (const float*)d_in[7];
    const float* b3 = (const float*)d_in[8];
    float* out = (float*)d_out;

    const int* src = ei;
    const int* dst = ei + NE;
    const int* ls = li;
    const int* ld = li + NL;

    // workspace carve-up (~43 MB)
    char* ws = (char*)d_ws;
    size_t off = 0;
    int* deg    = (int*)(ws + off); off += align256(NN * 4);
    int* cursor = (int*)(ws + off); off += align256(NB * 4);
    unsigned int* binbuf = (unsigned int*)(ws + off); off += align256((size_t)NB * BCAP * 4);
    unsigned short* colp = (unsigned short*)(ws + off); off += align256((size_t)NN * SLOTS * 2);
    unsigned short* Wtb  = (unsigned short*)(ws + off); off += align256(40960 * 2);
    // bufA: h1 (128-wide, rows 0..NN-1) + pad row at 50000.
    // h3 (64-wide) = bufA upper half; its pad row 50000 aliases bufA's.
    unsigned short* bufA = (unsigned short*)(ws + off); off += align256(((size_t)NN * 128 + 128) * 2);
    unsigned short* bufB = (unsigned short*)(ws + off); off += align256(((size_t)NN * 128 + 128) * 2);
    unsigned short* bufZ = (unsigned short*)(ws + off); off += align256((size_t)NN * 64 * 2);
    unsigned short* h3 = bufA + (size_t)25000 * 128;

    // ---- CSR build + W prep (+ zero pad rows) ----
    k_wprep<<<160, 256, 0, stream>>>(W1, W2, W3, Wtb, cursor,
                                     (unsigned int*)(bufA + (size_t)PADROW * 128),
                                     (unsigned int*)(bufB + (size_t)PADROW * 128));
    k_bin<<<391, 256, 0, stream>>>(src, dst, cursor, binbuf);
    k_csr<<<NB, 256, 0, stream>>>(binbuf, cursor, deg, colp);

    // ---- layer 1 GEMM: x -> bufA (h1 = dinv * x@W1, bf16) ----
    k_gemm1<<<782, 256, 0, stream>>>(x, Wtb, deg, bufA, NN);
    // ---- fused agg1(+b1,relu) + gemm2: bufA -> bufB (h2) ----
    k_agg_gemm<128><<<3125, 256, 0, stream>>>(bufA, deg, colp, b1, Wtb + 16384, bufB);
    // ---- fused agg2(+b2,relu) + gemm3: bufB -> h3 (64-wide) ----
    k_agg_gemm<64><<<3125, 256, 0, stream>>>(bufB, deg, colp, b2, Wtb + 32768, h3);
    // ---- agg3(+b3, no relu): h3 -> bufZ (z) ----
    k_agg64<<<12500, 256, 0, stream>>>(h3, deg, colp, b3, bufZ, NN);
    // ---- decode ----
    k_decode<<<6250, 256, 0, stream>>>(bufZ, ls, ld, out, NL);
}